// Round 14
// baseline (139.976 us; speedup 1.0000x reference)
//
#include <hip/hip_runtime.h>
#include <math.h>

#define NCH    1024
#define NN     64
#define CK     32                    // fused-fallback chunk
#define KSC    28.853900817779268f   // 20*log2(e): exp(-cost/0.05) = 2^((sim-1)*KSC)
#define WSB    4352                  // floats per record: 4096 gram + 4*64 stats

typedef __attribute__((ext_vector_type(8))) short bf16x8;
typedef __attribute__((ext_vector_type(4))) float f32x4;
typedef union { unsigned int u[4]; bf16x8 v; } FragCvt;

// stats accumulation from loaded registers (nodes 4*(l&15)+k of channel grp*4+(l>>4))
#define STAT_Q(v) { sqp[0]+=(v).x; q2p[0]=fmaf((v).x,(v).x,q2p[0]); \
                    sqp[1]+=(v).y; q2p[1]=fmaf((v).y,(v).y,q2p[1]); \
                    sqp[2]+=(v).z; q2p[2]=fmaf((v).z,(v).z,q2p[2]); \
                    sqp[3]+=(v).w; q2p[3]=fmaf((v).w,(v).w,q2p[3]); }
#define STAT_P(v) { spp[0]+=(v).x; p2p[0]=fmaf((v).x,(v).x,p2p[0]); \
                    spp[1]+=(v).y; p2p[1]=fmaf((v).y,(v).y,p2p[1]); \
                    spp[2]+=(v).z; p2p[2]=fmaf((v).z,(v).z,p2p[2]); \
                    spp[3]+=(v).w; p2p[3]=fmaf((v).w,(v).w,p2p[3]); }

// x -> hi (RNE bf16) + lo (trunc bf16); pack 2 elems into hi-dword / lo-dword.
// Error: |x - hi - lo| <= 2^-17|x|; dropping lo*lo in the Gram <= 2^-18|x||y|.
__device__ __forceinline__ void cvt2(float x0, float x1,
                                     unsigned int& hw, unsigned int& lw) {
    unsigned int u0 = __float_as_uint(x0), u1 = __float_as_uint(x1);
    unsigned int h0 = (u0 + 0x7FFFu + ((u0 >> 16) & 1u)) & 0xFFFF0000u;
    unsigned int h1 = (u1 + 0x7FFFu + ((u1 >> 16) & 1u)) & 0xFFFF0000u;
    hw = (h0 >> 16) | h1;
    float l0 = x0 - __uint_as_float(h0);
    float l1 = x1 - __uint_as_float(h1);
    lw = (__float_as_uint(l0) >> 16) | (__float_as_uint(l1) & 0xFFFF0000u);
}

// Transposed-at-write LDS: fp32 [n=64][k=32], word = n*32 + (k ^ (n&24)).
// k^(n&24) keeps k-octets (8-aligned runs) consecutive -> fragment (8 elems)
// = two aligned ds_read_b128. Read bank math: start bank = (8g ^ (n&24))&31,
// 8 lanes/start-bank x 4 words = 32 banks x 8 accesses = perfectly balanced.
__device__ __forceinline__ int ldword(int k, int n) {
    return n * 32 + (k ^ (n & 24));
}

// ===================== Kernel A: MFMA Gram partials, b128 frag reads =====================
// grid = (512<<LOGNS)/4 blocks x 256 thr; wave w = one ws record with a private
// 16KB LDS quadrant (no barriers, no cross-wave data). Per 32-ch chunk:
// float4 global loads -> stats from regs -> transpose-write into [n][k] swizzled
// LDS (64 scalar stores, ~4-way) -> per-frag 2x ds_read_b128 + bulk cvt2 ->
// 3x mfma_16x16x32_bf16 per 16x16 tile (hi*hi + hi*lo + lo*hi).
template<int LOGNS>
__global__ __launch_bounds__(256)
void gram_mfma4(const float* __restrict__ proto,
                const float* __restrict__ query,
                float* __restrict__ ws)
{
    constexpr int NCHUNK = 32 >> LOGNS;     // 32-channel chunks per record

    __shared__ __align__(16) char ldsbuf[65536];   // 4 x (Q fp32 8KB | P fp32 8KB)

    const int w   = threadIdx.x >> 6;        // record slot 0..3
    const int rid = blockIdx.x * 4 + w;      // global record id
    const int b = rid >> LOGNS, s = rid & ((1 << LOGNS) - 1);
    const int l = threadIdx.x & 63;
    const int lam = l & 15, g = l >> 4;

    float* const ldsQ = (float*)(ldsbuf + w * 16384);
    float* const ldsP = ldsQ + 2048;

    const float* __restrict__ qw = query + (size_t)b * 65536 + s * (65536 >> LOGNS);
    const float* __restrict__ pw = proto + (size_t)b * 65536 + s * (65536 >> LOGNS);

    f32x4 acc[4][4];
    #pragma unroll
    for (int r = 0; r < 4; ++r)
        #pragma unroll
        for (int c = 0; c < 4; ++c) {
            acc[r][c][0] = 0.0f; acc[r][c][1] = 0.0f;
            acc[r][c][2] = 0.0f; acc[r][c][3] = 0.0f;
        }
    float sqp[4] = {0,0,0,0}, q2p[4] = {0,0,0,0};
    float spp[4] = {0,0,0,0}, p2p[4] = {0,0,0,0};

    #pragma unroll 1
    for (int ch8 = 0; ch8 < NCHUNK; ++ch8) {
        // ---- load 32 channels (16 float4/lane), stats, transpose-write LDS ----
        float4 qv[8], pv[8];
        #pragma unroll
        for (int grp = 0; grp < 8; ++grp) {
            qv[grp] = *(const float4*)(qw + ch8 * 2048 + grp * 256 + 4 * l);
            pv[grp] = *(const float4*)(pw + ch8 * 2048 + grp * 256 + 4 * l);
        }
        #pragma unroll
        for (int grp = 0; grp < 8; ++grp) {
            STAT_Q(qv[grp]); STAT_P(pv[grp]);
            const int kk = grp * 4 + g;                 // chunk-local channel
            const float qe[4] = {qv[grp].x, qv[grp].y, qv[grp].z, qv[grp].w};
            const float pe[4] = {pv[grp].x, pv[grp].y, pv[grp].z, pv[grp].w};
            #pragma unroll
            for (int i = 0; i < 4; ++i) {
                const int n = 4 * lam + i;              // node owned
                const int wd = ldword(kk, n);
                ldsQ[wd] = qe[i];
                ldsP[wd] = pe[i];
            }
        }
        // ---- B frags (p side): 4 col-tiles, k-octet 8g..8g+7, 2 x b128 each ----
        unsigned int bh[4][4], bl[4][4];
        #pragma unroll
        for (int c = 0; c < 4; ++c) {
            const int n = c * 16 + lam;
            const int w0 = ldword(8 * g, n);            // 8-aligned start
            float4 x0 = *(const float4*)(ldsP + w0);
            float4 x1 = *(const float4*)(ldsP + w0 + 4);
            cvt2(x0.x, x0.y, bh[c][0], bl[c][0]);
            cvt2(x0.z, x0.w, bh[c][1], bl[c][1]);
            cvt2(x1.x, x1.y, bh[c][2], bl[c][2]);
            cvt2(x1.z, x1.w, bh[c][3], bl[c][3]);
        }
        // ---- A frags (q side) per row-tile + MFMAs ----
        #pragma unroll
        for (int r = 0; r < 4; ++r) {
            const int n = r * 16 + lam;
            const int w0 = ldword(8 * g, n);
            float4 x0 = *(const float4*)(ldsQ + w0);
            float4 x1 = *(const float4*)(ldsQ + w0 + 4);
            FragCvt ah, al;
            cvt2(x0.x, x0.y, ah.u[0], al.u[0]);
            cvt2(x0.z, x0.w, ah.u[1], al.u[1]);
            cvt2(x1.x, x1.y, ah.u[2], al.u[2]);
            cvt2(x1.z, x1.w, ah.u[3], al.u[3]);
            #pragma unroll
            for (int c = 0; c < 4; ++c) {
                FragCvt bhv, blv;
                bhv.u[0] = bh[c][0]; bhv.u[1] = bh[c][1];
                bhv.u[2] = bh[c][2]; bhv.u[3] = bh[c][3];
                blv.u[0] = bl[c][0]; blv.u[1] = bl[c][1];
                blv.u[2] = bl[c][2]; blv.u[3] = bl[c][3];
                acc[r][c] = __builtin_amdgcn_mfma_f32_16x16x32_bf16(ah.v, bhv.v, acc[r][c], 0, 0, 0);
                acc[r][c] = __builtin_amdgcn_mfma_f32_16x16x32_bf16(ah.v, blv.v, acc[r][c], 0, 0, 0);
                acc[r][c] = __builtin_amdgcn_mfma_f32_16x16x32_bf16(al.v, bhv.v, acc[r][c], 0, 0, 0);
            }
        }
    }

    // ---- stats reduce: lanes l, l^16, l^32, l^48 cover disjoint channels ----
    #pragma unroll
    for (int k = 0; k < 4; ++k) {
        sqp[k] += __shfl_xor(sqp[k], 16, 64); sqp[k] += __shfl_xor(sqp[k], 32, 64);
        q2p[k] += __shfl_xor(q2p[k], 16, 64); q2p[k] += __shfl_xor(q2p[k], 32, 64);
        spp[k] += __shfl_xor(spp[k], 16, 64); spp[k] += __shfl_xor(spp[k], 32, 64);
        p2p[k] += __shfl_xor(p2p[k], 16, 64); p2p[k] += __shfl_xor(p2p[k], 32, 64);
    }

    // ---- write record: C layout row=(lane>>4)*4+reg, col=lane&15 (verified m89/m91) ----
    float* __restrict__ wsb = ws + (size_t)rid * WSB;
    #pragma unroll
    for (int r = 0; r < 4; ++r)
        #pragma unroll
        for (int c = 0; c < 4; ++c)
            #pragma unroll
            for (int i = 0; i < 4; ++i)
                wsb[(r * 16 + 4 * g + i) * 64 + c * 16 + lam] = acc[r][c][i];
    if (l < 16) {
        #pragma unroll
        for (int k = 0; k < 4; ++k) {
            wsb[4096 +   0 + 4 * lam + k] = sqp[k];
            wsb[4096 +  64 + 4 * lam + k] = q2p[k];
            wsb[4096 + 128 + 4 * lam + k] = spp[k];
            wsb[4096 + 192 + 4 * lam + k] = p2p[k];
        }
    }
}

#define DOT16(KK, ARR) ({ \
    float4 x0 = *(const float4*)&ARR[sp4*16 +  0]; \
    float4 x1 = *(const float4*)&ARR[sp4*16 +  4]; \
    float4 x2 = *(const float4*)&ARR[sp4*16 +  8]; \
    float4 x3 = *(const float4*)&ARR[sp4*16 + 12]; \
    float a0 = 0.0f, a1 = 0.0f; \
    a0=fmaf(KK[0],x0.x,a0);  a1=fmaf(KK[1],x0.y,a1); \
    a0=fmaf(KK[2],x0.z,a0);  a1=fmaf(KK[3],x0.w,a1); \
    a0=fmaf(KK[4],x1.x,a0);  a1=fmaf(KK[5],x1.y,a1); \
    a0=fmaf(KK[6],x1.z,a0);  a1=fmaf(KK[7],x1.w,a1); \
    a0=fmaf(KK[8],x2.x,a0);  a1=fmaf(KK[9],x2.y,a1); \
    a0=fmaf(KK[10],x2.z,a0); a1=fmaf(KK[11],x2.w,a1); \
    a0=fmaf(KK[12],x3.x,a0); a1=fmaf(KK[13],x3.y,a1); \
    a0=fmaf(KK[14],x3.z,a0); a1=fmaf(KK[15],x3.w,a1); \
    a0 + a1; })

// ===================== Kernel B: combine + sim + K + Sinkhorn + logits (verified body) =====================
template<int NS>
__global__ __launch_bounds__(256)
void emd_solve(const float* __restrict__ ws, float* __restrict__ out)
{
    __shared__ __align__(16) float stage[16 * 64];
    __shared__ __align__(16) float Kl [NN][68];
    __shared__ __align__(16) float KTl[NN][68];
    __shared__ __align__(16) float statL[4][NN];
    __shared__ __align__(16) float uL[NN];
    __shared__ __align__(16) float vL[NN];
    __shared__ __align__(16) float rL[NN];
    __shared__ __align__(16) float cL[NN];
    __shared__ float redl[4];

    const int b  = blockIdx.x;
    const int t  = threadIdx.x;
    const int tr = t >> 4, tc = t & 15;
    const int n0 = tr * 4, m0 = tc * 4;

    const float* __restrict__ wsb = ws + (size_t)b * NS * WSB;

    float acc[4][4];
    #pragma unroll
    for (int i = 0; i < 4; ++i)
        #pragma unroll
        for (int j = 0; j < 4; ++j) acc[i][j] = 0.0f;
    #pragma unroll
    for (int s = 0; s < NS; ++s) {
        const float* __restrict__ g = wsb + s * WSB;
        #pragma unroll
        for (int i = 0; i < 4; ++i) {
            float4 v = *(const float4*)&g[(n0 + i) * 64 + m0];
            acc[i][0] += v.x; acc[i][1] += v.y; acc[i][2] += v.z; acc[i][3] += v.w;
        }
    }
    if (t < NN) {
        float s0 = 0, s1 = 0, s2 = 0, s3 = 0;
        #pragma unroll
        for (int s = 0; s < NS; ++s) {
            const float* __restrict__ g = wsb + s * WSB + 4096;
            s0 += g[t]; s1 += g[64 + t]; s2 += g[128 + t]; s3 += g[192 + t];
        }
        statL[0][t] = s0; statL[1][t] = s1; statL[2][t] = s2; statL[3][t] = s3;
    }
    #pragma unroll
    for (int i = 0; i < 4; ++i) {
        float s = acc[i][0] + acc[i][1] + acc[i][2] + acc[i][3];
        s += __shfl_xor(s, 1, 64); s += __shfl_xor(s, 2, 64);
        s += __shfl_xor(s, 4, 64); s += __shfl_xor(s, 8, 64);
        if (tc == 0) uL[n0 + i] = s;
    }
    #pragma unroll
    for (int j = 0; j < 4; ++j)
        stage[tr * 64 + m0 + j] = acc[0][j] + acc[1][j] + acc[2][j] + acc[3][j];
    __syncthreads();

    if (t < NN) {
        float cs = 0;
        #pragma unroll
        for (int i = 0; i < 16; ++i) cs += stage[i * 64 + t];
        float w2 = fmaxf(cs * (1.0f/64.0f), 0.0f) + 0.001f;
        float w1 = fmaxf(uL[t] * (1.0f/64.0f), 0.0f) + 0.001f;
        float s1 = w1, s2 = w2;
        #pragma unroll
        for (int m = 1; m < 64; m <<= 1) {
            s1 += __shfl_xor(s1, m, 64);
            s2 += __shfl_xor(s2, m, 64);
        }
        rL[t] = w1 / s1;
        cL[t] = w2 / s2;
        vL[t] = 1.0f;
    }
    {
        float nq_[4], np_[4], sqn[4], spm[4];
        #pragma unroll
        for (int i = 0; i < 4; ++i) {
            float sv  = statL[0][n0 + i];
            float var = statL[1][n0 + i] - sv * sv * (1.0f/1024.0f);
            nq_[i] = fmaxf(sqrtf(fmaxf(var, 0.0f)), 1e-8f);
            sqn[i] = sv;
        }
        #pragma unroll
        for (int j = 0; j < 4; ++j) {
            float sv  = statL[2][m0 + j];
            float var = statL[3][m0 + j] - sv * sv * (1.0f/1024.0f);
            np_[j] = fmaxf(sqrtf(fmaxf(var, 0.0f)), 1e-8f);
            spm[j] = sv;
        }
        #pragma unroll
        for (int i = 0; i < 4; ++i) {
            #pragma unroll
            for (int j = 0; j < 4; ++j) {
                float sim = (acc[i][j] - sqn[i] * spm[j] * (1.0f/1024.0f)) / (nq_[i] * np_[j]);
                acc[i][j] = sim;
                float Kv = exp2f((sim - 1.0f) * KSC);
                Kl [n0 + i][m0 + j] = Kv;
                KTl[m0 + j][n0 + i] = Kv;
            }
        }
    }
    __syncthreads();

    const int sn  = t >> 2;
    const int sp4 = t & 3;
    float Kr[16], KTr[16];
    #pragma unroll
    for (int jj = 0; jj < 4; ++jj) {
        float4 kv = *(const float4*)&Kl [sn][sp4 * 16 + jj * 4];
        float4 kt = *(const float4*)&KTl[sn][sp4 * 16 + jj * 4];
        Kr [jj*4+0]=kv.x; Kr [jj*4+1]=kv.y; Kr [jj*4+2]=kv.z; Kr [jj*4+3]=kv.w;
        KTr[jj*4+0]=kt.x; KTr[jj*4+1]=kt.y; KTr[jj*4+2]=kt.z; KTr[jj*4+3]=kt.w;
    }
    const float rreg = rL[sn];
    const float creg = cL[sn];

    for (int it = 0; it < 100; ++it) {
        float s = DOT16(Kr, vL);
        s += __shfl_xor(s, 1, 64); s += __shfl_xor(s, 2, 64);
        float u = rreg / fmaxf(s, 1e-30f);
        if (sp4 == 0) uL[sn] = u;
        __syncthreads();
        float s2 = DOT16(KTr, uL);
        s2 += __shfl_xor(s2, 1, 64); s2 += __shfl_xor(s2, 2, 64);
        float vv = creg / fmaxf(s2, 1e-30f);
        if (sp4 == 0) vL[sn] = vv;
        __syncthreads();
    }
    {
        float s = DOT16(Kr, vL);
        s += __shfl_xor(s, 1, 64); s += __shfl_xor(s, 2, 64);
        float u = rreg / fmaxf(s, 1e-30f);
        if (sp4 == 0) uL[sn] = u;
    }
    __syncthreads();

    float uu[4], vv_[4];
    #pragma unroll
    for (int i = 0; i < 4; ++i) uu[i]  = uL[n0 + i];
    #pragma unroll
    for (int j = 0; j < 4; ++j) vv_[j] = vL[m0 + j];
    float part = 0.0f;
    #pragma unroll
    for (int i = 0; i < 4; ++i) {
        #pragma unroll
        for (int j = 0; j < 4; ++j) {
            float sim = acc[i][j];
            float Kv  = exp2f((sim - 1.0f) * KSC);
            part = fmaf(sim * Kv, uu[i] * vv_[j], part);
        }
    }
    #pragma unroll
    for (int m = 1; m < 64; m <<= 1) part += __shfl_xor(part, m, 64);
    if ((t & 63) == 0) redl[t >> 6] = part;
    __syncthreads();
    if (t == 0) out[b] = (redl[0] + redl[1] + redl[2] + redl[3]) * (12.5f / 64.0f);
}

// ===================== Fallback: verified fused single-kernel path =====================
#define STAT_QF(v) { sqp[0]+=(v).x; q2p[0]=fmaf((v).x,(v).x,q2p[0]); \
                     sqp[1]+=(v).y; q2p[1]=fmaf((v).y,(v).y,q2p[1]); \
                     sqp[2]+=(v).z; q2p[2]=fmaf((v).z,(v).z,q2p[2]); \
                     sqp[3]+=(v).w; q2p[3]=fmaf((v).w,(v).w,q2p[3]); }
#define STAT_PF(v) { spp[0]+=(v).x; p2p[0]=fmaf((v).x,(v).x,p2p[0]); \
                     spp[1]+=(v).y; p2p[1]=fmaf((v).y,(v).y,p2p[1]); \
                     spp[2]+=(v).z; p2p[2]=fmaf((v).z,(v).z,p2p[2]); \
                     spp[3]+=(v).w; p2p[3]=fmaf((v).w,(v).w,p2p[3]); }

__global__ __launch_bounds__(256)
void deepemd_fused(const float* __restrict__ proto,
                   const float* __restrict__ query,
                   float* __restrict__ out)
{
    __shared__ __align__(16) float stage[2 * CK * NN];
    __shared__ __align__(16) float Kl [NN][68];
    __shared__ __align__(16) float KTl[NN][68];
    __shared__ __align__(16) float statL[4][NN];
    __shared__ __align__(16) float uL[NN];
    __shared__ __align__(16) float vL[NN];
    __shared__ __align__(16) float rL[NN];
    __shared__ __align__(16) float cL[NN];
    __shared__ float redl[4];

    const int b  = blockIdx.x;
    const int t  = threadIdx.x;
    const int tr = t >> 4, tc = t & 15;
    const int n0 = tr * 4, m0 = tc * 4;
    const int ofs = 4 * t;

    const float* __restrict__ pb = proto + (size_t)b * (NCH * NN);
    const float* __restrict__ qb = query + (size_t)b * (NCH * NN);

    float acc[4][4];
    #pragma unroll
    for (int i = 0; i < 4; ++i)
        #pragma unroll
        for (int j = 0; j < 4; ++j) acc[i][j] = 0.0f;
    float sqp[4] = {0,0,0,0}, q2p[4] = {0,0,0,0};
    float spp[4] = {0,0,0,0}, p2p[4] = {0,0,0,0};

    float4 qv0 = *(const float4*)(qb + ofs);
    float4 qv1 = *(const float4*)(qb + 1024 + ofs);
    float4 pv0 = *(const float4*)(pb + ofs);
    float4 pv1 = *(const float4*)(pb + 1024 + ofs);

    for (int ch = 0; ch < NCH / CK; ++ch) {
        if (ch) __syncthreads();
        *(float4*)&stage[       ofs] = qv0;
        *(float4*)&stage[1024 + ofs] = qv1;
        *(float4*)&stage[2048 + ofs] = pv0;
        *(float4*)&stage[3072 + ofs] = pv1;
        float4 nq0, nq1, np0, np1;
        const bool more = (ch + 1 < NCH / CK);
        if (more) {
            const float* qn = qb + (ch + 1) * 2048;
            const float* pn = pb + (ch + 1) * 2048;
            nq0 = *(const float4*)(qn + ofs);
            nq1 = *(const float4*)(qn + 1024 + ofs);
            np0 = *(const float4*)(pn + ofs);
            np1 = *(const float4*)(pn + 1024 + ofs);
        }
        STAT_QF(qv0); STAT_QF(qv1);
        STAT_PF(pv0); STAT_PF(pv1);
        __syncthreads();
        #pragma unroll 8
        for (int cc = 0; cc < CK; ++cc) {
            float4 a  = *(const float4*)&stage[cc * 64 + n0];
            float4 bb = *(const float4*)&stage[2048 + cc * 64 + m0];
            acc[0][0]=fmaf(a.x,bb.x,acc[0][0]); acc[0][1]=fmaf(a.x,bb.y,acc[0][1]);
            acc[0][2]=fmaf(a.x,bb.z,acc[0][2]); acc[0][3]=fmaf(a.x,bb.w,acc[0][3]);
            acc[1][0]=fmaf(a.y,bb.x,acc[1][0]); acc[1][1]=fmaf(a.y,bb.y,acc[1][1]);
            acc[1][2]=fmaf(a.y,bb.z,acc[1][2]); acc[1][3]=fmaf(a.y,bb.w,acc[1][3]);
            acc[2][0]=fmaf(a.z,bb.x,acc[2][0]); acc[2][1]=fmaf(a.z,bb.y,acc[2][1]);
            acc[2][2]=fmaf(a.z,bb.z,acc[2][2]); acc[2][3]=fmaf(a.z,bb.w,acc[2][3]);
            acc[3][0]=fmaf(a.w,bb.x,acc[3][0]); acc[3][1]=fmaf(a.w,bb.y,acc[3][1]);
            acc[3][2]=fmaf(a.w,bb.z,acc[3][2]); acc[3][3]=fmaf(a.w,bb.w,acc[3][3]);
        }
        if (more) { qv0 = nq0; qv1 = nq1; pv0 = np0; pv1 = np1; }
    }
    __syncthreads();

    #pragma unroll
    for (int i = 0; i < 4; ++i) {
        float s = acc[i][0] + acc[i][1] + acc[i][2] + acc[i][3];
        s += __shfl_xor(s, 1, 64); s += __shfl_xor(s, 2, 64);
        s += __shfl_xor(s, 4, 64); s += __shfl_xor(s, 8, 64);
        if (tc == 0) uL[n0 + i] = s;
    }
    #pragma unroll
    for (int k = 0; k < 4; ++k) {
        stage[t*16 +      k] = sqp[k];
        stage[t*16 +  4 + k] = q2p[k];
        stage[t*16 +  8 + k] = spp[k];
        stage[t*16 + 12 + k] = p2p[k];
    }
    __syncthreads();
    if (t < NN) {
        const int g = t >> 2, k = t & 3;
        float ssq = 0, sq2 = 0, ssp = 0, sp2 = 0;
        #pragma unroll
        for (int j = 0; j < 16; ++j) {
            const float* row = &stage[(j * 16 + g) * 16];
            ssq += row[k]; sq2 += row[4 + k]; ssp += row[8 + k]; sp2 += row[12 + k];
        }
        statL[0][t] = ssq; statL[1][t] = sq2; statL[2][t] = ssp; statL[3][t] = sp2;
    }
    __syncthreads();
    #pragma unroll
    for (int j = 0; j < 4; ++j)
        stage[tr * 64 + m0 + j] = acc[0][j] + acc[1][j] + acc[2][j] + acc[3][j];
    __syncthreads();
    if (t < NN) {
        float cs = 0;
        #pragma unroll
        for (int i = 0; i < 16; ++i) cs += stage[i * 64 + t];
        float w2 = fmaxf(cs * (1.0f/64.0f), 0.0f) + 0.001f;
        float w1 = fmaxf(uL[t] * (1.0f/64.0f), 0.0f) + 0.001f;
        float s1 = w1, s2 = w2;
        #pragma unroll
        for (int m = 1; m < 64; m <<= 1) {
            s1 += __shfl_xor(s1, m, 64);
            s2 += __shfl_xor(s2, m, 64);
        }
        rL[t] = w1 / s1;
        cL[t] = w2 / s2;
        vL[t] = 1.0f;
    }
    __syncthreads();

    {
        float nq_[4], np_[4], sqn[4], spm[4];
        #pragma unroll
        for (int i = 0; i < 4; ++i) {
            float sv  = statL[0][n0 + i];
            float var = statL[1][n0 + i] - sv * sv * (1.0f/1024.0f);
            nq_[i] = fmaxf(sqrtf(fmaxf(var, 0.0f)), 1e-8f);
            sqn[i] = sv;
        }
        #pragma unroll
        for (int j = 0; j < 4; ++j) {
            float sv  = statL[2][m0 + j];
            float var = statL[3][m0 + j] - sv * sv * (1.0f/1024.0f);
            np_[j] = fmaxf(sqrtf(fmaxf(var, 0.0f)), 1e-8f);
            spm[j] = sv;
        }
        #pragma unroll
        for (int i = 0; i < 4; ++i) {
            #pragma unroll
            for (int j = 0; j < 4; ++j) {
                float sim = (acc[i][j] - sqn[i] * spm[j] * (1.0f/1024.0f)) / (nq_[i] * np_[j]);
                acc[i][j] = sim;
                float Kv = exp2f((sim - 1.0f) * KSC);
                Kl [n0 + i][m0 + j] = Kv;
                KTl[m0 + j][n0 + i] = Kv;
            }
        }
    }
    __syncthreads();

    const int sn  = t >> 2;
    const int sp4 = t & 3;
    float Kr[16], KTr[16];
    #pragma unroll
    for (int jj = 0; jj < 4; ++jj) {
        float4 kv = *(const float4*)&Kl [sn][sp4 * 16 + jj * 4];
        float4 kt = *(const float4*)&KTl[sn][sp4 * 16 + jj * 4];
        Kr [jj*4+0]=kv.x; Kr [jj*4+1]=kv.y; Kr [jj*4+2]=kv.z; Kr [jj*4+3]=kv.w;
        KTr[jj*4+0]=kt.x; KTr[jj*4+1]=kt.y; KTr[jj*4+2]=kt.z; KTr[jj*4+3]=kt.w;
    }
    const float rreg = rL[sn];
    const float creg = cL[sn];

    for (int it = 0; it < 100; ++it) {
        float s = DOT16(Kr, vL);
        s += __shfl_xor(s, 1, 64); s += __shfl_xor(s, 2, 64);
        float u = rreg / fmaxf(s, 1e-30f);
        if (sp4 == 0) uL[sn] = u;
        __syncthreads();
        float s2 = DOT16(KTr, uL);
        s2 += __shfl_xor(s2, 1, 64); s2 += __shfl_xor(s2, 2, 64);
        float vv = creg / fmaxf(s2, 1e-30f);
        if (sp4 == 0) vL[sn] = vv;
        __syncthreads();
    }
    {
        float s = DOT16(Kr, vL);
        s += __shfl_xor(s, 1, 64); s += __shfl_xor(s, 2, 64);
        float u = rreg / fmaxf(s, 1e-30f);
        if (sp4 == 0) uL[sn] = u;
    }
    __syncthreads();

    float uu[4], vv_[4];
    #pragma unroll
    for (int i = 0; i < 4; ++i) uu[i]  = uL[n0 + i];
    #pragma unroll
    for (int j = 0; j < 4; ++j) vv_[j] = vL[m0 + j];
    float part = 0.0f;
    #pragma unroll
    for (int i = 0; i < 4; ++i) {
        #pragma unroll
        for (int j = 0; j < 4; ++j) {
            float sim = acc[i][j];
            float Kv  = exp2f((sim - 1.0f) * KSC);
            part = fmaf(sim * Kv, uu[i] * vv_[j], part);
        }
    }
    #pragma unroll
    for (int m = 1; m < 64; m <<= 1) part += __shfl_xor(part, m, 64);
    if ((t & 63) == 0) redl[t >> 6] = part;
    __syncthreads();
    if (t == 0) out[b] = (redl[0] + redl[1] + redl[2] + redl[3]) * (12.5f / 64.0f);
}

extern "C" void kernel_launch(void* const* d_in, const int* in_sizes, int n_in,
                              void* d_out, int out_size, void* d_ws, size_t ws_size,
                              hipStream_t stream) {
    const float* proto = (const float*)d_in[0];
    const float* query = (const float*)d_in[1];
    float* out = (float*)d_out;
    (void)in_sizes; (void)n_in; (void)out_size;

    const size_t need8 = (size_t)512 * 8 * WSB * sizeof(float);   // ~71.3 MB
    const size_t need4 = (size_t)512 * 4 * WSB * sizeof(float);   // ~35.7 MB
    if (ws_size >= need8) {
        gram_mfma4<3><<<dim3(512 * 8 / 4), dim3(256), 0, stream>>>(proto, query, (float*)d_ws);
        emd_solve<8><<<dim3(512),          dim3(256), 0, stream>>>((const float*)d_ws, out);
    } else if (ws_size >= need4) {
        gram_mfma4<2><<<dim3(512 * 4 / 4), dim3(256), 0, stream>>>(proto, query, (float*)d_ws);
        emd_solve<4><<<dim3(512),          dim3(256), 0, stream>>>((const float*)d_ws, out);
    } else {
        deepemd_fused<<<dim3(512), dim3(256), 0, stream>>>(proto, query, out);
    }
}

// Round 15
// 117.655 us; speedup vs baseline: 1.1897x; 1.1897x over previous
//
#include <hip/hip_runtime.h>
#include <math.h>

#define NCH    1024
#define NN     64
#define CK     32                    // fused-fallback chunk
#define KSC    28.853900817779268f   // 20*log2(e): exp(-cost/0.05) = 2^((sim-1)*KSC)
#define WSB    4352                  // floats per record: 4096 gram + 4*64 stats

typedef __attribute__((ext_vector_type(8))) short bf16x8;
typedef __attribute__((ext_vector_type(4))) float f32x4;
typedef union { unsigned int u[4]; bf16x8 v; } FragCvt;

// stats accumulation from loaded registers (nodes 4*(l&15)+k of channel grp*4+(l>>4))
#define STAT_Q(v) { sqp[0]+=(v).x; q2p[0]=fmaf((v).x,(v).x,q2p[0]); \
                    sqp[1]+=(v).y; q2p[1]=fmaf((v).y,(v).y,q2p[1]); \
                    sqp[2]+=(v).z; q2p[2]=fmaf((v).z,(v).z,q2p[2]); \
                    sqp[3]+=(v).w; q2p[3]=fmaf((v).w,(v).w,q2p[3]); }
#define STAT_P(v) { spp[0]+=(v).x; p2p[0]=fmaf((v).x,(v).x,p2p[0]); \
                    spp[1]+=(v).y; p2p[1]=fmaf((v).y,(v).y,p2p[1]); \
                    spp[2]+=(v).z; p2p[2]=fmaf((v).z,(v).z,p2p[2]); \
                    spp[3]+=(v).w; p2p[3]=fmaf((v).w,(v).w,p2p[3]); }

// x -> hi (RNE bf16) + lo (trunc bf16); pack 2 elems into hi-dword / lo-dword.
// Error: |x - hi - lo| <= 2^-17|x|; dropping lo*lo in the Gram <= 2^-18|x||y|.
__device__ __forceinline__ void cvt2(float x0, float x1,
                                     unsigned int& hw, unsigned int& lw) {
    unsigned int u0 = __float_as_uint(x0), u1 = __float_as_uint(x1);
    unsigned int h0 = (u0 + 0x7FFFu + ((u0 >> 16) & 1u)) & 0xFFFF0000u;
    unsigned int h1 = (u1 + 0x7FFFu + ((u1 >> 16) & 1u)) & 0xFFFF0000u;
    hw = (h0 >> 16) | h1;
    float l0 = x0 - __uint_as_float(h0);
    float l1 = x1 - __uint_as_float(h1);
    lw = (__float_as_uint(l0) >> 16) | (__float_as_uint(l1) & 0xFFFF0000u);
}

// Transposed-at-write LDS: fp32 [n=64][k=32], word = n*32 + (k ^ (n&24)).
// k^(n&24) keeps k-octets (8-aligned runs) consecutive -> fragment (8 elems)
// = two aligned ds_read_b128 (verified R14).
__device__ __forceinline__ int ldword(int k, int n) {
    return n * 32 + (k ^ (n & 24));
}

// ===================== Kernel A: MFMA Gram partials, chunk-level pipeline =====================
// grid = (512<<LOGNS)/4 blocks x 256 thr; wave w = one ws record with a private
// 16KB LDS quadrant (no barriers, no cross-wave data). Per 32-ch chunk:
//   {stats + transpose-store chunk ch from regs}   <- vmcnt drains here
//   {ISSUE chunk ch+1's 16 float4 global loads}    <- 16KB in flight ...
//   sched_barrier(0)
//   {frag b128 reads + cvt2 + 48 MFMAs of chunk ch} <- ... under this phase
// This keeps ~16KB/wave of HBM traffic in flight during compute (T14 pattern);
// R11-R14 had ZERO loads in flight during compute -> 10 GB/s/CU measured.
template<int LOGNS>
__global__ __launch_bounds__(256)
void gram_mfma4(const float* __restrict__ proto,
                const float* __restrict__ query,
                float* __restrict__ ws)
{
    constexpr int NCHUNK = 32 >> LOGNS;     // 32-channel chunks per record

    __shared__ __align__(16) char ldsbuf[65536];   // 4 x (Q fp32 8KB | P fp32 8KB)

    const int w   = threadIdx.x >> 6;        // record slot 0..3
    const int rid = blockIdx.x * 4 + w;      // global record id
    const int b = rid >> LOGNS, s = rid & ((1 << LOGNS) - 1);
    const int l = threadIdx.x & 63;
    const int lam = l & 15, g = l >> 4;

    float* const ldsQ = (float*)(ldsbuf + w * 16384);
    float* const ldsP = ldsQ + 2048;

    const float* __restrict__ qw = query + (size_t)b * 65536 + s * (65536 >> LOGNS);
    const float* __restrict__ pw = proto + (size_t)b * 65536 + s * (65536 >> LOGNS);

    f32x4 acc[4][4];
    #pragma unroll
    for (int r = 0; r < 4; ++r)
        #pragma unroll
        for (int c = 0; c < 4; ++c) {
            acc[r][c][0] = 0.0f; acc[r][c][1] = 0.0f;
            acc[r][c][2] = 0.0f; acc[r][c][3] = 0.0f;
        }
    float sqp[4] = {0,0,0,0}, q2p[4] = {0,0,0,0};
    float spp[4] = {0,0,0,0}, p2p[4] = {0,0,0,0};

    // prologue: chunk 0 into registers
    float4 qv[8], pv[8];
    #pragma unroll
    for (int grp = 0; grp < 8; ++grp) {
        qv[grp] = *(const float4*)(qw + grp * 256 + 4 * l);
        pv[grp] = *(const float4*)(pw + grp * 256 + 4 * l);
    }

    #pragma unroll 1
    for (int ch8 = 0; ch8 < NCHUNK; ++ch8) {
        // ---- stats + transpose-store chunk ch8 (consumes qv/pv; vmcnt drains) ----
        #pragma unroll
        for (int grp = 0; grp < 8; ++grp) {
            STAT_Q(qv[grp]); STAT_P(pv[grp]);
            const int kk = grp * 4 + g;                 // chunk-local channel
            const float qe[4] = {qv[grp].x, qv[grp].y, qv[grp].z, qv[grp].w};
            const float pe[4] = {pv[grp].x, pv[grp].y, pv[grp].z, pv[grp].w};
            #pragma unroll
            for (int i = 0; i < 4; ++i) {
                const int n = 4 * lam + i;              // node owned
                const int wd = ldword(kk, n);
                ldsQ[wd] = qe[i];
                ldsP[wd] = pe[i];
            }
        }
        // ---- ISSUE next chunk's loads (stay in flight under the compute phase) ----
        if (ch8 + 1 < NCHUNK) {
            #pragma unroll
            for (int grp = 0; grp < 8; ++grp) {
                qv[grp] = *(const float4*)(qw + (ch8 + 1) * 2048 + grp * 256 + 4 * l);
                pv[grp] = *(const float4*)(pw + (ch8 + 1) * 2048 + grp * 256 + 4 * l);
            }
        }
        __builtin_amdgcn_sched_barrier(0);   // pin: loads issued before compute

        // ---- B frags (p side): 4 col-tiles, k-octet 8g..8g+7, 2 x b128 each ----
        unsigned int bh[4][4], bl[4][4];
        #pragma unroll
        for (int c = 0; c < 4; ++c) {
            const int n = c * 16 + lam;
            const int w0 = ldword(8 * g, n);            // 8-aligned start
            float4 x0 = *(const float4*)(ldsP + w0);
            float4 x1 = *(const float4*)(ldsP + w0 + 4);
            cvt2(x0.x, x0.y, bh[c][0], bl[c][0]);
            cvt2(x0.z, x0.w, bh[c][1], bl[c][1]);
            cvt2(x1.x, x1.y, bh[c][2], bl[c][2]);
            cvt2(x1.z, x1.w, bh[c][3], bl[c][3]);
        }
        // ---- A frags (q side) per row-tile + MFMAs ----
        #pragma unroll
        for (int r = 0; r < 4; ++r) {
            const int n = r * 16 + lam;
            const int w0 = ldword(8 * g, n);
            float4 x0 = *(const float4*)(ldsQ + w0);
            float4 x1 = *(const float4*)(ldsQ + w0 + 4);
            FragCvt ah, al;
            cvt2(x0.x, x0.y, ah.u[0], al.u[0]);
            cvt2(x0.z, x0.w, ah.u[1], al.u[1]);
            cvt2(x1.x, x1.y, ah.u[2], al.u[2]);
            cvt2(x1.z, x1.w, ah.u[3], al.u[3]);
            #pragma unroll
            for (int c = 0; c < 4; ++c) {
                FragCvt bhv, blv;
                bhv.u[0] = bh[c][0]; bhv.u[1] = bh[c][1];
                bhv.u[2] = bh[c][2]; bhv.u[3] = bh[c][3];
                blv.u[0] = bl[c][0]; blv.u[1] = bl[c][1];
                blv.u[2] = bl[c][2]; blv.u[3] = bl[c][3];
                acc[r][c] = __builtin_amdgcn_mfma_f32_16x16x32_bf16(ah.v, bhv.v, acc[r][c], 0, 0, 0);
                acc[r][c] = __builtin_amdgcn_mfma_f32_16x16x32_bf16(ah.v, blv.v, acc[r][c], 0, 0, 0);
                acc[r][c] = __builtin_amdgcn_mfma_f32_16x16x32_bf16(al.v, bhv.v, acc[r][c], 0, 0, 0);
            }
        }
    }

    // ---- stats reduce: lanes l, l^16, l^32, l^48 cover disjoint channels ----
    #pragma unroll
    for (int k = 0; k < 4; ++k) {
        sqp[k] += __shfl_xor(sqp[k], 16, 64); sqp[k] += __shfl_xor(sqp[k], 32, 64);
        q2p[k] += __shfl_xor(q2p[k], 16, 64); q2p[k] += __shfl_xor(q2p[k], 32, 64);
        spp[k] += __shfl_xor(spp[k], 16, 64); spp[k] += __shfl_xor(spp[k], 32, 64);
        p2p[k] += __shfl_xor(p2p[k], 16, 64); p2p[k] += __shfl_xor(p2p[k], 32, 64);
    }

    // ---- write record: C layout row=(lane>>4)*4+reg, col=lane&15 (verified m89/m91) ----
    float* __restrict__ wsb = ws + (size_t)rid * WSB;
    #pragma unroll
    for (int r = 0; r < 4; ++r)
        #pragma unroll
        for (int c = 0; c < 4; ++c)
            #pragma unroll
            for (int i = 0; i < 4; ++i)
                wsb[(r * 16 + 4 * g + i) * 64 + c * 16 + lam] = acc[r][c][i];
    if (l < 16) {
        #pragma unroll
        for (int k = 0; k < 4; ++k) {
            wsb[4096 +   0 + 4 * lam + k] = sqp[k];
            wsb[4096 +  64 + 4 * lam + k] = q2p[k];
            wsb[4096 + 128 + 4 * lam + k] = spp[k];
            wsb[4096 + 192 + 4 * lam + k] = p2p[k];
        }
    }
}

#define DOT16(KK, ARR) ({ \
    float4 x0 = *(const float4*)&ARR[sp4*16 +  0]; \
    float4 x1 = *(const float4*)&ARR[sp4*16 +  4]; \
    float4 x2 = *(const float4*)&ARR[sp4*16 +  8]; \
    float4 x3 = *(const float4*)&ARR[sp4*16 + 12]; \
    float a0 = 0.0f, a1 = 0.0f; \
    a0=fmaf(KK[0],x0.x,a0);  a1=fmaf(KK[1],x0.y,a1); \
    a0=fmaf(KK[2],x0.z,a0);  a1=fmaf(KK[3],x0.w,a1); \
    a0=fmaf(KK[4],x1.x,a0);  a1=fmaf(KK[5],x1.y,a1); \
    a0=fmaf(KK[6],x1.z,a0);  a1=fmaf(KK[7],x1.w,a1); \
    a0=fmaf(KK[8],x2.x,a0);  a1=fmaf(KK[9],x2.y,a1); \
    a0=fmaf(KK[10],x2.z,a0); a1=fmaf(KK[11],x2.w,a1); \
    a0=fmaf(KK[12],x3.x,a0); a1=fmaf(KK[13],x3.y,a1); \
    a0=fmaf(KK[14],x3.z,a0); a1=fmaf(KK[15],x3.w,a1); \
    a0 + a1; })

// ===================== Kernel B: combine + sim + K + Sinkhorn + logits (verified body) =====================
template<int NS>
__global__ __launch_bounds__(256)
void emd_solve(const float* __restrict__ ws, float* __restrict__ out)
{
    __shared__ __align__(16) float stage[16 * 64];
    __shared__ __align__(16) float Kl [NN][68];
    __shared__ __align__(16) float KTl[NN][68];
    __shared__ __align__(16) float statL[4][NN];
    __shared__ __align__(16) float uL[NN];
    __shared__ __align__(16) float vL[NN];
    __shared__ __align__(16) float rL[NN];
    __shared__ __align__(16) float cL[NN];
    __shared__ float redl[4];

    const int b  = blockIdx.x;
    const int t  = threadIdx.x;
    const int tr = t >> 4, tc = t & 15;
    const int n0 = tr * 4, m0 = tc * 4;

    const float* __restrict__ wsb = ws + (size_t)b * NS * WSB;

    float acc[4][4];
    #pragma unroll
    for (int i = 0; i < 4; ++i)
        #pragma unroll
        for (int j = 0; j < 4; ++j) acc[i][j] = 0.0f;
    #pragma unroll
    for (int s = 0; s < NS; ++s) {
        const float* __restrict__ g = wsb + s * WSB;
        #pragma unroll
        for (int i = 0; i < 4; ++i) {
            float4 v = *(const float4*)&g[(n0 + i) * 64 + m0];
            acc[i][0] += v.x; acc[i][1] += v.y; acc[i][2] += v.z; acc[i][3] += v.w;
        }
    }
    if (t < NN) {
        float s0 = 0, s1 = 0, s2 = 0, s3 = 0;
        #pragma unroll
        for (int s = 0; s < NS; ++s) {
            const float* __restrict__ g = wsb + s * WSB + 4096;
            s0 += g[t]; s1 += g[64 + t]; s2 += g[128 + t]; s3 += g[192 + t];
        }
        statL[0][t] = s0; statL[1][t] = s1; statL[2][t] = s2; statL[3][t] = s3;
    }
    #pragma unroll
    for (int i = 0; i < 4; ++i) {
        float s = acc[i][0] + acc[i][1] + acc[i][2] + acc[i][3];
        s += __shfl_xor(s, 1, 64); s += __shfl_xor(s, 2, 64);
        s += __shfl_xor(s, 4, 64); s += __shfl_xor(s, 8, 64);
        if (tc == 0) uL[n0 + i] = s;
    }
    #pragma unroll
    for (int j = 0; j < 4; ++j)
        stage[tr * 64 + m0 + j] = acc[0][j] + acc[1][j] + acc[2][j] + acc[3][j];
    __syncthreads();

    if (t < NN) {
        float cs = 0;
        #pragma unroll
        for (int i = 0; i < 16; ++i) cs += stage[i * 64 + t];
        float w2 = fmaxf(cs * (1.0f/64.0f), 0.0f) + 0.001f;
        float w1 = fmaxf(uL[t] * (1.0f/64.0f), 0.0f) + 0.001f;
        float s1 = w1, s2 = w2;
        #pragma unroll
        for (int m = 1; m < 64; m <<= 1) {
            s1 += __shfl_xor(s1, m, 64);
            s2 += __shfl_xor(s2, m, 64);
        }
        rL[t] = w1 / s1;
        cL[t] = w2 / s2;
        vL[t] = 1.0f;
    }
    {
        float nq_[4], np_[4], sqn[4], spm[4];
        #pragma unroll
        for (int i = 0; i < 4; ++i) {
            float sv  = statL[0][n0 + i];
            float var = statL[1][n0 + i] - sv * sv * (1.0f/1024.0f);
            nq_[i] = fmaxf(sqrtf(fmaxf(var, 0.0f)), 1e-8f);
            sqn[i] = sv;
        }
        #pragma unroll
        for (int j = 0; j < 4; ++j) {
            float sv  = statL[2][m0 + j];
            float var = statL[3][m0 + j] - sv * sv * (1.0f/1024.0f);
            np_[j] = fmaxf(sqrtf(fmaxf(var, 0.0f)), 1e-8f);
            spm[j] = sv;
        }
        #pragma unroll
        for (int i = 0; i < 4; ++i) {
            #pragma unroll
            for (int j = 0; j < 4; ++j) {
                float sim = (acc[i][j] - sqn[i] * spm[j] * (1.0f/1024.0f)) / (nq_[i] * np_[j]);
                acc[i][j] = sim;
                float Kv = exp2f((sim - 1.0f) * KSC);
                Kl [n0 + i][m0 + j] = Kv;
                KTl[m0 + j][n0 + i] = Kv;
            }
        }
    }
    __syncthreads();

    const int sn  = t >> 2;
    const int sp4 = t & 3;
    float Kr[16], KTr[16];
    #pragma unroll
    for (int jj = 0; jj < 4; ++jj) {
        float4 kv = *(const float4*)&Kl [sn][sp4 * 16 + jj * 4];
        float4 kt = *(const float4*)&KTl[sn][sp4 * 16 + jj * 4];
        Kr [jj*4+0]=kv.x; Kr [jj*4+1]=kv.y; Kr [jj*4+2]=kv.z; Kr [jj*4+3]=kv.w;
        KTr[jj*4+0]=kt.x; KTr[jj*4+1]=kt.y; KTr[jj*4+2]=kt.z; KTr[jj*4+3]=kt.w;
    }
    const float rreg = rL[sn];
    const float creg = cL[sn];

    for (int it = 0; it < 100; ++it) {
        float s = DOT16(Kr, vL);
        s += __shfl_xor(s, 1, 64); s += __shfl_xor(s, 2, 64);
        float u = rreg / fmaxf(s, 1e-30f);
        if (sp4 == 0) uL[sn] = u;
        __syncthreads();
        float s2 = DOT16(KTr, uL);
        s2 += __shfl_xor(s2, 1, 64); s2 += __shfl_xor(s2, 2, 64);
        float vv = creg / fmaxf(s2, 1e-30f);
        if (sp4 == 0) vL[sn] = vv;
        __syncthreads();
    }
    {
        float s = DOT16(Kr, vL);
        s += __shfl_xor(s, 1, 64); s += __shfl_xor(s, 2, 64);
        float u = rreg / fmaxf(s, 1e-30f);
        if (sp4 == 0) uL[sn] = u;
    }
    __syncthreads();

    float uu[4], vv_[4];
    #pragma unroll
    for (int i = 0; i < 4; ++i) uu[i]  = uL[n0 + i];
    #pragma unroll
    for (int j = 0; j < 4; ++j) vv_[j] = vL[m0 + j];
    float part = 0.0f;
    #pragma unroll
    for (int i = 0; i < 4; ++i) {
        #pragma unroll
        for (int j = 0; j < 4; ++j) {
            float sim = acc[i][j];
            float Kv  = exp2f((sim - 1.0f) * KSC);
            part = fmaf(sim * Kv, uu[i] * vv_[j], part);
        }
    }
    #pragma unroll
    for (int m = 1; m < 64; m <<= 1) part += __shfl_xor(part, m, 64);
    if ((t & 63) == 0) redl[t >> 6] = part;
    __syncthreads();
    if (t == 0) out[b] = (redl[0] + redl[1] + redl[2] + redl[3]) * (12.5f / 64.0f);
}

// ===================== Fallback: verified fused single-kernel path =====================
#define STAT_QF(v) { sqp[0]+=(v).x; q2p[0]=fmaf((v).x,(v).x,q2p[0]); \
                     sqp[1]+=(v).y; q2p[1]=fmaf((v).y,(v).y,q2p[1]); \
                     sqp[2]+=(v).z; q2p[2]=fmaf((v).z,(v).z,q2p[2]); \
                     sqp[3]+=(v).w; q2p[3]=fmaf((v).w,(v).w,q2p[3]); }
#define STAT_PF(v) { spp[0]+=(v).x; p2p[0]=fmaf((v).x,(v).x,p2p[0]); \
                     spp[1]+=(v).y; p2p[1]=fmaf((v).y,(v).y,p2p[1]); \
                     spp[2]+=(v).z; p2p[2]=fmaf((v).z,(v).z,p2p[2]); \
                     spp[3]+=(v).w; p2p[3]=fmaf((v).w,(v).w,p2p[3]); }

__global__ __launch_bounds__(256)
void deepemd_fused(const float* __restrict__ proto,
                   const float* __restrict__ query,
                   float* __restrict__ out)
{
    __shared__ __align__(16) float stage[2 * CK * NN];
    __shared__ __align__(16) float Kl [NN][68];
    __shared__ __align__(16) float KTl[NN][68];
    __shared__ __align__(16) float statL[4][NN];
    __shared__ __align__(16) float uL[NN];
    __shared__ __align__(16) float vL[NN];
    __shared__ __align__(16) float rL[NN];
    __shared__ __align__(16) float cL[NN];
    __shared__ float redl[4];

    const int b  = blockIdx.x;
    const int t  = threadIdx.x;
    const int tr = t >> 4, tc = t & 15;
    const int n0 = tr * 4, m0 = tc * 4;
    const int ofs = 4 * t;

    const float* __restrict__ pb = proto + (size_t)b * (NCH * NN);
    const float* __restrict__ qb = query + (size_t)b * (NCH * NN);

    float acc[4][4];
    #pragma unroll
    for (int i = 0; i < 4; ++i)
        #pragma unroll
        for (int j = 0; j < 4; ++j) acc[i][j] = 0.0f;
    float sqp[4] = {0,0,0,0}, q2p[4] = {0,0,0,0};
    float spp[4] = {0,0,0,0}, p2p[4] = {0,0,0,0};

    float4 qv0 = *(const float4*)(qb + ofs);
    float4 qv1 = *(const float4*)(qb + 1024 + ofs);
    float4 pv0 = *(const float4*)(pb + ofs);
    float4 pv1 = *(const float4*)(pb + 1024 + ofs);

    for (int ch = 0; ch < NCH / CK; ++ch) {
        if (ch) __syncthreads();
        *(float4*)&stage[       ofs] = qv0;
        *(float4*)&stage[1024 + ofs] = qv1;
        *(float4*)&stage[2048 + ofs] = pv0;
        *(float4*)&stage[3072 + ofs] = pv1;
        float4 nq0, nq1, np0, np1;
        const bool more = (ch + 1 < NCH / CK);
        if (more) {
            const float* qn = qb + (ch + 1) * 2048;
            const float* pn = pb + (ch + 1) * 2048;
            nq0 = *(const float4*)(qn + ofs);
            nq1 = *(const float4*)(qn + 1024 + ofs);
            np0 = *(const float4*)(pn + ofs);
            np1 = *(const float4*)(pn + 1024 + ofs);
        }
        STAT_QF(qv0); STAT_QF(qv1);
        STAT_PF(pv0); STAT_PF(pv1);
        __syncthreads();
        #pragma unroll 8
        for (int cc = 0; cc < CK; ++cc) {
            float4 a  = *(const float4*)&stage[cc * 64 + n0];
            float4 bb = *(const float4*)&stage[2048 + cc * 64 + m0];
            acc[0][0]=fmaf(a.x,bb.x,acc[0][0]); acc[0][1]=fmaf(a.x,bb.y,acc[0][1]);
            acc[0][2]=fmaf(a.x,bb.z,acc[0][2]); acc[0][3]=fmaf(a.x,bb.w,acc[0][3]);
            acc[1][0]=fmaf(a.y,bb.x,acc[1][0]); acc[1][1]=fmaf(a.y,bb.y,acc[1][1]);
            acc[1][2]=fmaf(a.y,bb.z,acc[1][2]); acc[1][3]=fmaf(a.y,bb.w,acc[1][3]);
            acc[2][0]=fmaf(a.z,bb.x,acc[2][0]); acc[2][1]=fmaf(a.z,bb.y,acc[2][1]);
            acc[2][2]=fmaf(a.z,bb.z,acc[2][2]); acc[2][3]=fmaf(a.z,bb.w,acc[2][3]);
            acc[3][0]=fmaf(a.w,bb.x,acc[3][0]); acc[3][1]=fmaf(a.w,bb.y,acc[3][1]);
            acc[3][2]=fmaf(a.w,bb.z,acc[3][2]); acc[3][3]=fmaf(a.w,bb.w,acc[3][3]);
        }
        if (more) { qv0 = nq0; qv1 = nq1; pv0 = np0; pv1 = np1; }
    }
    __syncthreads();

    #pragma unroll
    for (int i = 0; i < 4; ++i) {
        float s = acc[i][0] + acc[i][1] + acc[i][2] + acc[i][3];
        s += __shfl_xor(s, 1, 64); s += __shfl_xor(s, 2, 64);
        s += __shfl_xor(s, 4, 64); s += __shfl_xor(s, 8, 64);
        if (tc == 0) uL[n0 + i] = s;
    }
    #pragma unroll
    for (int k = 0; k < 4; ++k) {
        stage[t*16 +      k] = sqp[k];
        stage[t*16 +  4 + k] = q2p[k];
        stage[t*16 +  8 + k] = spp[k];
        stage[t*16 + 12 + k] = p2p[k];
    }
    __syncthreads();
    if (t < NN) {
        const int g = t >> 2, k = t & 3;
        float ssq = 0, sq2 = 0, ssp = 0, sp2 = 0;
        #pragma unroll
        for (int j = 0; j < 16; ++j) {
            const float* row = &stage[(j * 16 + g) * 16];
            ssq += row[k]; sq2 += row[4 + k]; ssp += row[8 + k]; sp2 += row[12 + k];
        }
        statL[0][t] = ssq; statL[1][t] = sq2; statL[2][t] = ssp; statL[3][t] = sp2;
    }
    __syncthreads();
    #pragma unroll
    for (int j = 0; j < 4; ++j)
        stage[tr * 64 + m0 + j] = acc[0][j] + acc[1][j] + acc[2][j] + acc[3][j];
    __syncthreads();
    if (t < NN) {
        float cs = 0;
        #pragma unroll
        for (int i = 0; i < 16; ++i) cs += stage[i * 64 + t];
        float w2 = fmaxf(cs * (1.0f/64.0f), 0.0f) + 0.001f;
        float w1 = fmaxf(uL[t] * (1.0f/64.0f), 0.0f) + 0.001f;
        float s1 = w1, s2 = w2;
        #pragma unroll
        for (int m = 1; m < 64; m <<= 1) {
            s1 += __shfl_xor(s1, m, 64);
            s2 += __shfl_xor(s2, m, 64);
        }
        rL[t] = w1 / s1;
        cL[t] = w2 / s2;
        vL[t] = 1.0f;
    }
    __syncthreads();

    {
        float nq_[4], np_[4], sqn[4], spm[4];
        #pragma unroll
        for (int i = 0; i < 4; ++i) {
            float sv  = statL[0][n0 + i];
            float var = statL[1][n0 + i] - sv * sv * (1.0f/1024.0f);
            nq_[i] = fmaxf(sqrtf(fmaxf(var, 0.0f)), 1e-8f);
            sqn[i] = sv;
        }
        #pragma unroll
        for (int j = 0; j < 4; ++j) {
            float sv  = statL[2][m0 + j];
            float var = statL[3][m0 + j] - sv * sv * (1.0f/1024.0f);
            np_[j] = fmaxf(sqrtf(fmaxf(var, 0.0f)), 1e-8f);
            spm[j] = sv;
        }
        #pragma unroll
        for (int i = 0; i < 4; ++i) {
            #pragma unroll
            for (int j = 0; j < 4; ++j) {
                float sim = (acc[i][j] - sqn[i] * spm[j] * (1.0f/1024.0f)) / (nq_[i] * np_[j]);
                acc[i][j] = sim;
                float Kv = exp2f((sim - 1.0f) * KSC);
                Kl [n0 + i][m0 + j] = Kv;
                KTl[m0 + j][n0 + i] = Kv;
            }
        }
    }
    __syncthreads();

    const int sn  = t >> 2;
    const int sp4 = t & 3;
    float Kr[16], KTr[16];
    #pragma unroll
    for (int jj = 0; jj < 4; ++jj) {
        float4 kv = *(const float4*)&Kl [sn][sp4 * 16 + jj * 4];
        float4 kt = *(const float4*)&KTl[sn][sp4 * 16 + jj * 4];
        Kr [jj*4+0]=kv.x; Kr [jj*4+1]=kv.y; Kr [jj*4+2]=kv.z; Kr [jj*4+3]=kv.w;
        KTr[jj*4+0]=kt.x; KTr[jj*4+1]=kt.y; KTr[jj*4+2]=kt.z; KTr[jj*4+3]=kt.w;
    }
    const float rreg = rL[sn];
    const float creg = cL[sn];

    for (int it = 0; it < 100; ++it) {
        float s = DOT16(Kr, vL);
        s += __shfl_xor(s, 1, 64); s += __shfl_xor(s, 2, 64);
        float u = rreg / fmaxf(s, 1e-30f);
        if (sp4 == 0) uL[sn] = u;
        __syncthreads();
        float s2 = DOT16(KTr, uL);
        s2 += __shfl_xor(s2, 1, 64); s2 += __shfl_xor(s2, 2, 64);
        float vv = creg / fmaxf(s2, 1e-30f);
        if (sp4 == 0) vL[sn] = vv;
        __syncthreads();
    }
    {
        float s = DOT16(Kr, vL);
        s += __shfl_xor(s, 1, 64); s += __shfl_xor(s, 2, 64);
        float u = rreg / fmaxf(s, 1e-30f);
        if (sp4 == 0) uL[sn] = u;
    }
    __syncthreads();

    float uu[4], vv_[4];
    #pragma unroll
    for (int i = 0; i < 4; ++i) uu[i]  = uL[n0 + i];
    #pragma unroll
    for (int j = 0; j < 4; ++j) vv_[j] = vL[m0 + j];
    float part = 0.0f;
    #pragma unroll
    for (int i = 0; i < 4; ++i) {
        #pragma unroll
        for (int j = 0; j < 4; ++j) {
            float sim = acc[i][j];
            float Kv  = exp2f((sim - 1.0f) * KSC);
            part = fmaf(sim * Kv, uu[i] * vv_[j], part);
        }
    }
    #pragma unroll
    for (int m = 1; m < 64; m <<= 1) part += __shfl_xor(part, m, 64);
    if ((t & 63) == 0) redl[t >> 6] = part;
    __syncthreads();
    if (t == 0) out[b] = (redl[0] + redl[1] + redl[2] + redl[3]) * (12.5f / 64.0f);
}

extern "C" void kernel_launch(void* const* d_in, const int* in_sizes, int n_in,
                              void* d_out, int out_size, void* d_ws, size_t ws_size,
                              hipStream_t stream) {
    const float* proto = (const float*)d_in[0];
    const float* query = (const float*)d_in[1];
    float* out = (float*)d_out;
    (void)in_sizes; (void)n_in; (void)out_size;

    const size_t need4 = (size_t)512 * 4 * WSB * sizeof(float);   // ~35.7 MB
    if (ws_size >= need4) {
        gram_mfma4<2><<<dim3(512 * 4 / 4), dim3(256), 0, stream>>>(proto, query, (float*)d_ws);
        emd_solve<4><<<dim3(512),          dim3(256), 0, stream>>>((const float*)d_ws, out);
    } else {
        deepemd_fused<<<dim3(512), dim3(256), 0, stream>>>(proto, query, out);
    }
}